// Round 12
// baseline (229.112 us; speedup 1.0000x reference)
//
#include <hip/hip_runtime.h>
#include <hip/hip_bf16.h>

#define BB 8
#define CC 64
#define NN 4096
#define LOG2E 1.44269504088896340736f

typedef short bf16x8 __attribute__((ext_vector_type(8)));
typedef float f32x16 __attribute__((ext_vector_type(16)));
typedef unsigned int uint4v __attribute__((ext_vector_type(4)));

__device__ __forceinline__ unsigned cvt_pk_bf16(float lo, float hi) {
    unsigned r;
    asm("v_cvt_pk_bf16_f32 %0, %1, %2" : "=v"(r) : "v"(lo), "v"(hi));
    return r;
}

// Schraudolph fast exp2 (2 full-rate VALU ops).
__device__ __forceinline__ float fast_exp2(float x) {
    int i = (int)__builtin_fmaf(x, 8388608.f, 1064992087.f);
    return __builtin_bit_cast(float, i);
}

__device__ __forceinline__ void keep_u(unsigned x) { asm volatile("" :: "v"(x)); }
__device__ __forceinline__ void keep_v(bf16x8 v) {
    uint4v u = __builtin_bit_cast(uint4v, v);
    asm volatile("" :: "v"(u[0]), "v"(u[1]), "v"(u[2]), "v"(u[3]));
}

// Workspace fragment layouts (all bf16 shorts):
//  qw   [b][n][8]
//  kfrag[b][tile32][lane64][8]  lane<32: K[key][d], lane>=32: zeros
//  vfrag[b][tile64][slab8][lane64][8]

// ---------------------------------------------------------------------------
// Kernel 1: QKV projection.
// ---------------------------------------------------------------------------
__global__ __launch_bounds__(256) void qkv_kernel(
    const float* __restrict__ X,
    const float* __restrict__ Wq, const float* __restrict__ bq,
    const float* __restrict__ Wk, const float* __restrict__ bk,
    const float* __restrict__ Wv, const float* __restrict__ bv,
    unsigned short* __restrict__ qw, unsigned short* __restrict__ kfrag,
    unsigned short* __restrict__ vfrag)
{
    __shared__ float wbuf[64 * 16];
    __shared__ float bsh[16];
    __shared__ short vsh[16][264];

    const int t = threadIdx.x;
    const int grp = blockIdx.x % 5;
    const int tile = blockIdx.x / 5;
    const int b = tile >> 4;
    const int nb = (tile & 15) << 8;
    const int n = nb + t;

    if (grp == 0) {
        for (int i = t; i < 512; i += 256) {
            int o = i >> 6, c = i & 63;
            wbuf[c * 16 + o]     = Wq[i];
            wbuf[c * 16 + 8 + o] = Wk[i];
        }
        if (t < 8) { bsh[t] = bq[t]; bsh[8 + t] = bk[t]; }
    } else {
        const int cbase = (grp - 1) * 16;
        for (int i = t; i < 1024; i += 256) {
            int o = i >> 6, c = i & 63;
            wbuf[c * 16 + o] = Wv[(cbase + o) * 64 + c];
        }
        if (t < 16) bsh[t] = bv[cbase + t];
    }
    __syncthreads();

    float a[16];
    #pragma unroll
    for (int j = 0; j < 16; j++) a[j] = bsh[j];

    const float* xp = X + (size_t)b * CC * NN + n;
    for (int c = 0; c < 64; c++) {
        float xc = xp[(size_t)c * NN];
        const float4* w4 = (const float4*)&wbuf[c * 16];
        float4 w0 = w4[0], w1 = w4[1], w2 = w4[2], w3 = w4[3];
        a[0]  += w0.x * xc; a[1]  += w0.y * xc; a[2]  += w0.z * xc; a[3]  += w0.w * xc;
        a[4]  += w1.x * xc; a[5]  += w1.y * xc; a[6]  += w1.z * xc; a[7]  += w1.w * xc;
        a[8]  += w2.x * xc; a[9]  += w2.y * xc; a[10] += w2.z * xc; a[11] += w2.w * xc;
        a[12] += w3.x * xc; a[13] += w3.y * xc; a[14] += w3.z * xc; a[15] += w3.w * xc;
    }

    if (grp == 0) {
        alignas(16) __hip_bfloat16 qb8[8], kb8[8];
        #pragma unroll
        for (int d = 0; d < 8; d++) {
            qb8[d] = __float2bfloat16(a[d] * LOG2E);
            kb8[d] = __float2bfloat16(a[8 + d]);
        }
        const size_t g = (size_t)b * NN + n;
        *(int4*)(qw + g * 8) = *(const int4*)qb8;
        size_t kf = ((size_t)b * 128 + (n >> 5)) * 512;
        *(int4*)(kfrag + kf + (size_t)(n & 31) * 8) = *(const int4*)kb8;
        *(int4*)(kfrag + kf + (size_t)(32 + (n & 31)) * 8) = make_int4(0, 0, 0, 0);
    } else {
        const int cbase = (grp - 1) * 16;
        const int qb0 = cbase & 31, ct = cbase >> 5;
        #pragma unroll
        for (int j = 0; j < 16; j++)
            vsh[j][t] = __builtin_bit_cast(short, __float2bfloat16(a[j]));
        __syncthreads();
        #pragma unroll
        for (int rr = 0; rr < 2; ++rr) {
            int r = 2 * t + rr;
            int qq = r & 15, hh = (r >> 4) & 1, gg = (r >> 5) & 3, tau = r >> 7;
            int n0 = tau * 64 + gg * 16 + hh * 8;
            int4 val = *(const int4*)&vsh[qq][n0];
            int gtile = (nb >> 6) + tau;
            size_t dst = ((size_t)(b * 64 + gtile)) * 4096
                       + (size_t)(gg * 2 + ct) * 512
                       + (size_t)(32 * hh + qb0 + qq) * 8;
            *(int4*)(vfrag + dst) = val;
        }
    }
}

// ---------------------------------------------------------------------------
// ABLATION kernel. MODE: 0=full  1=no-exp  2=no-PV (no V loads, no PV MFMA)
// 3=mem-only (loads + keepalive). REP repeats whole pass so dur_us beats the
// ~43us harness fills into the rocprof top-5. Writes to dump (scratch).
// KS=4 geometry, identical to the real attn below.
// ---------------------------------------------------------------------------
template<int MODE, int REP>
__global__ __launch_bounds__(256, 2) void attn_abl(
    const unsigned short* __restrict__ qw,
    const unsigned short* __restrict__ kfrag,
    const unsigned short* __restrict__ vfrag,
    float* __restrict__ dump)
{
    const int t = threadIdx.x;
    const int w = t >> 6, lane = t & 63;
    const int h = lane >> 5, q = lane & 31;

    const int nwg = gridDim.x;
    const int cpx = nwg >> 3;
    const int bid = (blockIdx.x & 7) * cpx + (blockIdx.x >> 3);

    const int qtile = bid & 15;
    const int b = (bid >> 4) & 7;
    const int ks = bid >> 7;

    const int qbase = qtile * 256 + w * 64;

    bf16x8 qfA = {}, qfB = {};
    if (h == 0) {
        qfA = *(const bf16x8*)(qw + ((size_t)b * NN + qbase + q) * 8);
        qfB = *(const bf16x8*)(qw + ((size_t)b * NN + qbase + 32 + q) * 8);
    }

    f32x16 accA0 = {}, accA1 = {}, accB0 = {}, accB1 = {};
    float lsumA = 0.f, lsumB = 0.f;

    const int NT = NN / 4 / 64;
    const unsigned short* kb = kfrag + (size_t)b * 65536
                             + (size_t)ks * NT * 1024 + (size_t)lane * 8;
    const unsigned short* vbp = vfrag + (size_t)b * 262144
                              + (size_t)ks * NT * 4096 + (size_t)lane * 8;

    auto phase = [&](const f32x16& sA, const f32x16& sB,
                     bf16x8 va, bf16x8 vb2, bf16x8 vc, bf16x8 vd) {
        float pa[16], pb[16];
        #pragma unroll
        for (int r = 0; r < 16; ++r) {
            if (MODE == 1) { pa[r] = sA[r]; pb[r] = sB[r]; }
            else           { pa[r] = fast_exp2(sA[r]); pb[r] = fast_exp2(sB[r]); }
        }
        {
            float a0 = 0.f, a1 = 0.f, b0 = 0.f, b1 = 0.f;
            #pragma unroll
            for (int r = 0; r < 8; ++r) {
                a0 += pa[r]; a1 += pa[8 + r];
                b0 += pb[r]; b1 += pb[8 + r];
            }
            lsumA += a0 + a1;
            lsumB += b0 + b1;
        }
        unsigned ka[8], kb2[8];
        #pragma unroll
        for (int j = 0; j < 8; ++j) {
            ka[j]  = cvt_pk_bf16(pa[2 * j], pa[2 * j + 1]);
            kb2[j] = cvt_pk_bf16(pb[2 * j], pb[2 * j + 1]);
        }
        if (MODE == 2) {
            #pragma unroll
            for (int j = 0; j < 8; ++j) { keep_u(ka[j]); keep_u(kb2[j]); }
            return;
        }
        __builtin_amdgcn_s_setprio(1);
        #pragma unroll
        for (int g2 = 0; g2 < 2; ++g2) {
            const unsigned* pga = &ka[4 * g2];
            auto ra = __builtin_amdgcn_permlane32_swap(pga[2], pga[0], false, false);
            auto rb = __builtin_amdgcn_permlane32_swap(pga[3], pga[1], false, false);
            uint4v bua = { ra[1], rb[1], ra[0], rb[0] };
            bf16x8 pfA = __builtin_bit_cast(bf16x8, bua);
            const unsigned* pgb = &kb2[4 * g2];
            auto rc = __builtin_amdgcn_permlane32_swap(pgb[2], pgb[0], false, false);
            auto rd = __builtin_amdgcn_permlane32_swap(pgb[3], pgb[1], false, false);
            uint4v bub = { rc[1], rd[1], rc[0], rd[0] };
            bf16x8 pfB = __builtin_bit_cast(bf16x8, bub);
            bf16x8 vx = g2 ? vc : va;
            bf16x8 vy = g2 ? vd : vb2;
            accA0 = __builtin_amdgcn_mfma_f32_32x32x16_bf16(vx, pfA, accA0, 0, 0, 0);
            accA1 = __builtin_amdgcn_mfma_f32_32x32x16_bf16(vy, pfA, accA1, 0, 0, 0);
            accB0 = __builtin_amdgcn_mfma_f32_32x32x16_bf16(vx, pfB, accB0, 0, 0, 0);
            accB1 = __builtin_amdgcn_mfma_f32_32x32x16_bf16(vy, pfB, accB1, 0, 0, 0);
        }
        __builtin_amdgcn_s_setprio(0);
    };

    for (int rep = 0; rep < REP; ++rep) {
        bf16x8 kc0 = *(const bf16x8*)kb;
        bf16x8 kc1 = *(const bf16x8*)(kb + 512);

        for (int it = 0; it < NT; ++it) {
            if (MODE == 3) {
                const unsigned short* kp = kb + (size_t)it * 1024;
                const unsigned short* vp = vbp + (size_t)it * 4096;
                bf16x8 k0 = *(const bf16x8*)kp;
                bf16x8 k1 = *(const bf16x8*)(kp + 512);
                keep_v(k0); keep_v(k1);
                #pragma unroll
                for (int s = 0; s < 8; ++s) {
                    bf16x8 vv = *(const bf16x8*)(vp + (size_t)s * 512);
                    keep_v(vv);
                }
                continue;
            }
            const unsigned short* vp = vbp + (size_t)it * 4096;
            bf16x8 v0, v1, v2, v3, v4, v5, v6, v7;
            if (MODE != 2) {
                v0 = *(const bf16x8*)(vp);
                v1 = *(const bf16x8*)(vp + 512);
                v2 = *(const bf16x8*)(vp + 1024);
                v3 = *(const bf16x8*)(vp + 1536);
                v4 = *(const bf16x8*)(vp + 2048);
                v5 = *(const bf16x8*)(vp + 2560);
                v6 = *(const bf16x8*)(vp + 3072);
                v7 = *(const bf16x8*)(vp + 3584);
            }
            const int nit = (it + 1 < NT) ? it + 1 : it;
            const unsigned short* knp = kb + (size_t)nit * 1024;
            bf16x8 kn0 = *(const bf16x8*)knp;
            bf16x8 kn1 = *(const bf16x8*)(knp + 512);

            {
                f32x16 sA = __builtin_amdgcn_mfma_f32_32x32x16_bf16(kc0, qfA, (f32x16){}, 0, 0, 0);
                f32x16 sB = __builtin_amdgcn_mfma_f32_32x32x16_bf16(kc0, qfB, (f32x16){}, 0, 0, 0);
                phase(sA, sB, v0, v1, v2, v3);
            }
            {
                f32x16 sA = __builtin_amdgcn_mfma_f32_32x32x16_bf16(kc1, qfA, (f32x16){}, 0, 0, 0);
                f32x16 sB = __builtin_amdgcn_mfma_f32_32x32x16_bf16(kc1, qfB, (f32x16){}, 0, 0, 0);
                phase(sA, sB, v4, v5, v6, v7);
            }
            kc0 = kn0;
            kc1 = kn1;
        }
    }

    // anchor writes
    float* dp = dump + ((size_t)blockIdx.x * 256 + t) * 8;
    dp[0] = lsumA; dp[1] = lsumB;
    dp[2] = accA0[0] + accA1[0];
    dp[3] = accB0[0] + accB1[0];
    dp[4] = accA0[15]; dp[5] = accB1[15];
    dp[6] = 1.f; dp[7] = (float)MODE;
}

// ---------------------------------------------------------------------------
// Kernel 2: real MFMA flash attention (R10 structure, KS template).
// ---------------------------------------------------------------------------
template<int KS, bool FUSE>
__global__ __launch_bounds__(256, 2) void attn_kernel(
    const unsigned short* __restrict__ qw,
    const unsigned short* __restrict__ kfrag,
    const unsigned short* __restrict__ vfrag,
    unsigned short* __restrict__ pout, float* __restrict__ pl,
    const float* __restrict__ X, const float* __restrict__ gamma,
    float* __restrict__ out)
{
    const int t = threadIdx.x;
    const int w = t >> 6, lane = t & 63;
    const int h = lane >> 5, q = lane & 31;

    const int nwg = gridDim.x;
    const int cpx = nwg >> 3;
    const int bid = (blockIdx.x & 7) * cpx + (blockIdx.x >> 3);

    const int qtile = bid & 15;
    const int b = (bid >> 4) & 7;
    const int ks = bid >> 7;

    const int qbase = qtile * 256 + w * 64;

    bf16x8 qfA = {}, qfB = {};
    if (h == 0) {
        qfA = *(const bf16x8*)(qw + ((size_t)b * NN + qbase + q) * 8);
        qfB = *(const bf16x8*)(qw + ((size_t)b * NN + qbase + 32 + q) * 8);
    }

    f32x16 accA0 = {}, accA1 = {}, accB0 = {}, accB1 = {};
    float lsumA = 0.f, lsumB = 0.f;

    const int NT = NN / KS / 64;
    const unsigned short* kb = kfrag + (size_t)b * 65536
                             + (size_t)ks * NT * 1024 + (size_t)lane * 8;
    const unsigned short* vbp = vfrag + (size_t)b * 262144
                              + (size_t)ks * NT * 4096 + (size_t)lane * 8;

    auto phase = [&](const f32x16& sA, const f32x16& sB,
                     bf16x8 va, bf16x8 vb2, bf16x8 vc, bf16x8 vd) {
        float pa[16], pb[16];
        #pragma unroll
        for (int r = 0; r < 16; ++r) { pa[r] = fast_exp2(sA[r]); pb[r] = fast_exp2(sB[r]); }
        {
            float a0 = 0.f, a1 = 0.f, b0 = 0.f, b1 = 0.f;
            #pragma unroll
            for (int r = 0; r < 8; ++r) {
                a0 += pa[r]; a1 += pa[8 + r];
                b0 += pb[r]; b1 += pb[8 + r];
            }
            lsumA += a0 + a1;
            lsumB += b0 + b1;
        }
        unsigned ka[8], kb2[8];
        #pragma unroll
        for (int j = 0; j < 8; ++j) {
            ka[j]  = cvt_pk_bf16(pa[2 * j], pa[2 * j + 1]);
            kb2[j] = cvt_pk_bf16(pb[2 * j], pb[2 * j + 1]);
        }
        __builtin_amdgcn_s_setprio(1);
        #pragma unroll
        for (int g2 = 0; g2 < 2; ++g2) {
            const unsigned* pga = &ka[4 * g2];
            auto ra = __builtin_amdgcn_permlane32_swap(pga[2], pga[0], false, false);
            auto rb = __builtin_amdgcn_permlane32_swap(pga[3], pga[1], false, false);
            uint4v bua = { ra[1], rb[1], ra[0], rb[0] };
            bf16x8 pfA = __builtin_bit_cast(bf16x8, bua);
            const unsigned* pgb = &kb2[4 * g2];
            auto rc = __builtin_amdgcn_permlane32_swap(pgb[2], pgb[0], false, false);
            auto rd = __builtin_amdgcn_permlane32_swap(pgb[3], pgb[1], false, false);
            uint4v bub = { rc[1], rd[1], rc[0], rd[0] };
            bf16x8 pfB = __builtin_bit_cast(bf16x8, bub);

            bf16x8 vx = g2 ? vc : va;
            bf16x8 vy = g2 ? vd : vb2;
            accA0 = __builtin_amdgcn_mfma_f32_32x32x16_bf16(vx, pfA, accA0, 0, 0, 0);
            accA1 = __builtin_amdgcn_mfma_f32_32x32x16_bf16(vy, pfA, accA1, 0, 0, 0);
            accB0 = __builtin_amdgcn_mfma_f32_32x32x16_bf16(vx, pfB, accB0, 0, 0, 0);
            accB1 = __builtin_amdgcn_mfma_f32_32x32x16_bf16(vy, pfB, accB1, 0, 0, 0);
        }
        __builtin_amdgcn_s_setprio(0);
    };

    bf16x8 kc0 = *(const bf16x8*)kb;
    bf16x8 kc1 = *(const bf16x8*)(kb + 512);

    for (int it = 0; it < NT; ++it) {
        const unsigned short* vp = vbp + (size_t)it * 4096;
        bf16x8 v0 = *(const bf16x8*)(vp);
        bf16x8 v1 = *(const bf16x8*)(vp + 512);
        bf16x8 v2 = *(const bf16x8*)(vp + 1024);
        bf16x8 v3 = *(const bf16x8*)(vp + 1536);
        bf16x8 v4 = *(const bf16x8*)(vp + 2048);
        bf16x8 v5 = *(const bf16x8*)(vp + 2560);
        bf16x8 v6 = *(const bf16x8*)(vp + 3072);
        bf16x8 v7 = *(const bf16x8*)(vp + 3584);

        const int nit = (it + 1 < NT) ? it + 1 : it;
        const unsigned short* knp = kb + (size_t)nit * 1024;
        bf16x8 kn0 = *(const bf16x8*)knp;
        bf16x8 kn1 = *(const bf16x8*)(knp + 512);

        {
            f32x16 sA = __builtin_amdgcn_mfma_f32_32x32x16_bf16(kc0, qfA, (f32x16){}, 0, 0, 0);
            f32x16 sB = __builtin_amdgcn_mfma_f32_32x32x16_bf16(kc0, qfB, (f32x16){}, 0, 0, 0);
            phase(sA, sB, v0, v1, v2, v3);
        }
        {
            f32x16 sA = __builtin_amdgcn_mfma_f32_32x32x16_bf16(kc1, qfA, (f32x16){}, 0, 0, 0);
            f32x16 sB = __builtin_amdgcn_mfma_f32_32x32x16_bf16(kc1, qfB, (f32x16){}, 0, 0, 0);
            phase(sA, sB, v4, v5, v6, v7);
        }
        kc0 = kn0;
        kc1 = kn1;
    }

    auto rsA = __builtin_amdgcn_permlane32_swap(__builtin_bit_cast(unsigned, lsumA),
                                                __builtin_bit_cast(unsigned, lsumA), false, false);
    float ltotA = __builtin_bit_cast(float, rsA[0]) + __builtin_bit_cast(float, rsA[1]);
    auto rsB = __builtin_amdgcn_permlane32_swap(__builtin_bit_cast(unsigned, lsumB),
                                                __builtin_bit_cast(unsigned, lsumB), false, false);
    float ltotB = __builtin_bit_cast(float, rsB[0]) + __builtin_bit_cast(float, rsB[1]);

    const float gm = FUSE ? gamma[0] : 0.f;

    #pragma unroll
    for (int sub = 0; sub < 2; ++sub) {
        const int n = qbase + sub * 32 + q;
        const float ltot = sub ? ltotB : ltotA;
        const f32x16& a0 = sub ? accB0 : accA0;
        const f32x16& a1 = sub ? accB1 : accA1;
        if (FUSE) {
            const float inv = 1.f / ltot;
            #pragma unroll
            for (int ct = 0; ct < 2; ++ct) {
                const f32x16& a = ct ? a1 : a0;
                #pragma unroll
                for (int r = 0; r < 16; ++r) {
                    int c = ct * 32 + (r & 3) + 8 * (r >> 2) + 4 * h;
                    size_t idx = ((size_t)(b * CC + c)) * NN + n;
                    out[idx] = X[idx] + gm * a[r] * inv;
                }
            }
        } else {
            unsigned short* po = pout + (size_t)ks * BB * CC * NN;
            #pragma unroll
            for (int ct = 0; ct < 2; ++ct) {
                const f32x16& a = ct ? a1 : a0;
                #pragma unroll
                for (int r = 0; r < 16; ++r) {
                    int c = ct * 32 + (r & 3) + 8 * (r >> 2) + 4 * h;
                    po[((size_t)(b * CC + c)) * NN + n] =
                        __builtin_bit_cast(unsigned short, __float2bfloat16(a[r]));
                }
            }
            if (h == 0) pl[((size_t)(ks * BB + b)) * NN + n] = ltot;
        }
    }
}

// ---------------------------------------------------------------------------
// Kernel 3: combine KS key-splits (bf16 partials) + epilogue.
// ---------------------------------------------------------------------------
template<int KS>
__global__ __launch_bounds__(256) void combine_kernel(
    const unsigned short* __restrict__ pout, const float* __restrict__ pl,
    const float* __restrict__ X, const float* __restrict__ gamma,
    float* __restrict__ out)
{
    const int idx = blockIdx.x * 256 + threadIdx.x;
    const int n4 = idx & 1023;
    const int c  = (idx >> 10) & 63;
    const int b  = idx >> 16;
    const int n0 = n4 * 4;
    const float gm = gamma[0];
    const size_t base = ((size_t)(b * CC + c)) * NN + n0;

    float4 s = make_float4(0.f, 0.f, 0.f, 0.f);
    float4 L = make_float4(0.f, 0.f, 0.f, 0.f);
    #pragma unroll
    for (int ks = 0; ks < KS; ++ks) {
        ushort4 sv = *(const ushort4*)(pout + (size_t)ks * BB * CC * NN + base);
        float4 lv = *(const float4*)(pl + ((size_t)(ks * BB + b)) * NN + n0);
        s.x += __bfloat162float(__builtin_bit_cast(__hip_bfloat16, sv.x));
        s.y += __bfloat162float(__builtin_bit_cast(__hip_bfloat16, sv.y));
        s.z += __bfloat162float(__builtin_bit_cast(__hip_bfloat16, sv.z));
        s.w += __bfloat162float(__builtin_bit_cast(__hip_bfloat16, sv.w));
        L.x += lv.x; L.y += lv.y; L.z += lv.z; L.w += lv.w;
    }
    float4 x = *(const float4*)(X + base);
    float4 o;
    o.x = x.x + gm * s.x / L.x;
    o.y = x.y + gm * s.y / L.y;
    o.z = x.z + gm * s.z / L.z;
    o.w = x.w + gm * s.w / L.w;
    *(float4*)(out + base) = o;
}

// ---------------------------------------------------------------------------
extern "C" void kernel_launch(void* const* d_in, const int* in_sizes, int n_in,
                              void* d_out, int out_size, void* d_ws, size_t ws_size,
                              hipStream_t stream) {
    const float* X  = (const float*)d_in[0];
    const float* Wq = (const float*)d_in[1];
    const float* bq = (const float*)d_in[2];
    const float* Wk = (const float*)d_in[3];
    const float* bk = (const float*)d_in[4];
    const float* Wv = (const float*)d_in[5];
    const float* bv = (const float*)d_in[6];
    const float* gm = (const float*)d_in[7];
    float* out = (float*)d_out;

    unsigned short* qw    = (unsigned short*)d_ws;
    unsigned short* kfrag = qw + (size_t)BB * NN * 8;
    unsigned short* vfrag = kfrag + (size_t)BB * 128 * 512;
    unsigned short* pout  = vfrag + (size_t)BB * 64 * 4096;
    float* pl = (float*)(pout + (size_t)4 * BB * CC * NN);

    const size_t qkv_bytes = ((size_t)BB * NN * 8 + (size_t)BB * 128 * 512
                            + (size_t)BB * 64 * 4096) * 2;
    const size_t need4 = qkv_bytes + (size_t)4 * BB * CC * NN * 2 + (size_t)4 * BB * NN * 4;
    const size_t dump_need = (size_t)128 * 1024 * 1024 + (size_t)512 * 256 * 8 * 4;

    qkv_kernel<<<dim3(640), dim3(256), 0, stream>>>(X, Wq, bq, Wk, bk, Wv, bv, qw, kfrag, vfrag);

    // ---- ablation dispatches (profiling; write to scratch high region) ----
    if (ws_size >= dump_need) {
        float* dump = (float*)((char*)d_ws + (size_t)128 * 1024 * 1024);
        attn_abl<0, 2><<<dim3(512), dim3(256), 0, stream>>>(qw, kfrag, vfrag, dump);  // FULL
        attn_abl<1, 2><<<dim3(512), dim3(256), 0, stream>>>(qw, kfrag, vfrag, dump);  // NOEXP
        attn_abl<2, 2><<<dim3(512), dim3(256), 0, stream>>>(qw, kfrag, vfrag, dump);  // NOPV
        attn_abl<3, 4><<<dim3(512), dim3(256), 0, stream>>>(qw, kfrag, vfrag, dump);  // MEMONLY
    }

    // ---- real pipeline (KS=4, best-known config) ----
    if (ws_size >= need4) {
        attn_kernel<4, false><<<dim3(512), dim3(256), 0, stream>>>(
            qw, kfrag, vfrag, pout, pl, X, gm, out);
        combine_kernel<4><<<dim3((BB * CC * NN / 4) / 256), dim3(256), 0, stream>>>(
            pout, pl, X, gm, out);
    } else {
        attn_kernel<1, true><<<dim3(128), dim3(256), 0, stream>>>(
            qw, kfrag, vfrag, nullptr, nullptr, X, gm, out);
    }
}

// Round 13
// 57.709 us; speedup vs baseline: 3.9701x; 3.9701x over previous
//
#include <hip/hip_runtime.h>
#include <hip/hip_bf16.h>

#define BB 8
#define CC 64
#define NN 4096
#define LOG2E 1.44269504088896340736f

typedef short bf16x8 __attribute__((ext_vector_type(8)));
typedef float f32x16 __attribute__((ext_vector_type(16)));
typedef unsigned int uint4v __attribute__((ext_vector_type(4)));

__device__ __forceinline__ unsigned cvt_pk_bf16(float lo, float hi) {
    unsigned r;
    asm("v_cvt_pk_bf16_f32 %0, %1, %2" : "=v"(r) : "v"(lo), "v"(hi));
    return r;
}

// Schraudolph fast exp2 (2 full-rate VALU ops, no trans pipe).
__device__ __forceinline__ float fast_exp2(float x) {
    int i = (int)__builtin_fmaf(x, 8388608.f, 1064992087.f);
    return __builtin_bit_cast(float, i);
}

__device__ __forceinline__ void vmwait3()  { asm volatile("s_waitcnt vmcnt(3)" ::: "memory"); }
__device__ __forceinline__ void vmwait2()  { asm volatile("s_waitcnt vmcnt(2)" ::: "memory"); }
__device__ __forceinline__ void vmwait0()  { asm volatile("s_waitcnt vmcnt(0)" ::: "memory"); }
__device__ __forceinline__ void lgkmwait0(){ asm volatile("s_waitcnt lgkmcnt(0)" ::: "memory"); }

__device__ __forceinline__ void glds16(const void* g, void* l) {
    __builtin_amdgcn_global_load_lds(
        (const __attribute__((address_space(1))) unsigned int*)g,
        (__attribute__((address_space(3))) unsigned int*)l, 16, 0, 0);
}

// Workspace fragment layouts (all bf16 shorts):
//  qw   [b][n][8]
//  kfrag[b][tile32][lane64][8]  lane<32: K[key][d], lane>=32: zeros
//  vfrag[b][tile64][slab8][lane64][8]

// ---------------------------------------------------------------------------
// Kernel 1: QKV projection, 5 groups x 128 position-tiles = 640 blocks.
// ---------------------------------------------------------------------------
__global__ __launch_bounds__(256) void qkv_kernel(
    const float* __restrict__ X,
    const float* __restrict__ Wq, const float* __restrict__ bq,
    const float* __restrict__ Wk, const float* __restrict__ bk,
    const float* __restrict__ Wv, const float* __restrict__ bv,
    unsigned short* __restrict__ qw, unsigned short* __restrict__ kfrag,
    unsigned short* __restrict__ vfrag)
{
    __shared__ float wbuf[64 * 16];
    __shared__ float bsh[16];
    __shared__ short vsh[16][264];

    const int t = threadIdx.x;
    const int grp = blockIdx.x % 5;
    const int tile = blockIdx.x / 5;
    const int b = tile >> 4;
    const int nb = (tile & 15) << 8;
    const int n = nb + t;

    if (grp == 0) {
        for (int i = t; i < 512; i += 256) {
            int o = i >> 6, c = i & 63;
            wbuf[c * 16 + o]     = Wq[i];
            wbuf[c * 16 + 8 + o] = Wk[i];
        }
        if (t < 8) { bsh[t] = bq[t]; bsh[8 + t] = bk[t]; }
    } else {
        const int cbase = (grp - 1) * 16;
        for (int i = t; i < 1024; i += 256) {
            int o = i >> 6, c = i & 63;
            wbuf[c * 16 + o] = Wv[(cbase + o) * 64 + c];
        }
        if (t < 16) bsh[t] = bv[cbase + t];
    }
    __syncthreads();

    float a[16];
    #pragma unroll
    for (int j = 0; j < 16; j++) a[j] = bsh[j];

    const float* xp = X + (size_t)b * CC * NN + n;
    for (int c = 0; c < 64; c++) {
        float xc = xp[(size_t)c * NN];
        const float4* w4 = (const float4*)&wbuf[c * 16];
        float4 w0 = w4[0], w1 = w4[1], w2 = w4[2], w3 = w4[3];
        a[0]  += w0.x * xc; a[1]  += w0.y * xc; a[2]  += w0.z * xc; a[3]  += w0.w * xc;
        a[4]  += w1.x * xc; a[5]  += w1.y * xc; a[6]  += w1.z * xc; a[7]  += w1.w * xc;
        a[8]  += w2.x * xc; a[9]  += w2.y * xc; a[10] += w2.z * xc; a[11] += w2.w * xc;
        a[12] += w3.x * xc; a[13] += w3.y * xc; a[14] += w3.z * xc; a[15] += w3.w * xc;
    }

    if (grp == 0) {
        alignas(16) __hip_bfloat16 qb8[8], kb8[8];
        #pragma unroll
        for (int d = 0; d < 8; d++) {
            qb8[d] = __float2bfloat16(a[d] * LOG2E);
            kb8[d] = __float2bfloat16(a[8 + d]);
        }
        const size_t g = (size_t)b * NN + n;
        *(int4*)(qw + g * 8) = *(const int4*)qb8;
        size_t kf = ((size_t)b * 128 + (n >> 5)) * 512;
        *(int4*)(kfrag + kf + (size_t)(n & 31) * 8) = *(const int4*)kb8;
        *(int4*)(kfrag + kf + (size_t)(32 + (n & 31)) * 8) = make_int4(0, 0, 0, 0);
    } else {
        const int cbase = (grp - 1) * 16;
        const int qb0 = cbase & 31, ct = cbase >> 5;
        #pragma unroll
        for (int j = 0; j < 16; j++)
            vsh[j][t] = __builtin_bit_cast(short, __float2bfloat16(a[j]));
        __syncthreads();
        #pragma unroll
        for (int rr = 0; rr < 2; ++rr) {
            int r = 2 * t + rr;
            int qq = r & 15, hh = (r >> 4) & 1, gg = (r >> 5) & 3, tau = r >> 7;
            int n0 = tau * 64 + gg * 16 + hh * 8;
            int4 val = *(const int4*)&vsh[qq][n0];
            int gtile = (nb >> 6) + tau;
            size_t dst = ((size_t)(b * 64 + gtile)) * 4096
                       + (size_t)(gg * 2 + ct) * 512
                       + (size_t)(32 * hh + qb0 + qq) * 8;
            *(int4*)(vfrag + dst) = val;
        }
    }
}

// ---------------------------------------------------------------------------
// Kernel 2: MFMA flash attention with LDS double-buffer + COUNTED vmcnt
// pipeline (never drains to 0 in the main loop): per 64-key tile, issue next
// stage's global_load_lds, wait only for the PREVIOUS stage (vmcnt(3|2)),
// raw s_barrier, compute from LDS, lgkmcnt(0), s_barrier. 4 waves share the
// staged tile (V global traffic /4). Compute = R10's register pipeline with
// fragments via conflict-free linear ds_read_b128.
// ---------------------------------------------------------------------------
template<int KS, bool FUSE>
__global__ __launch_bounds__(256, 2) void attn_kernel(
    const unsigned short* __restrict__ qw,
    const unsigned short* __restrict__ kfrag,
    const unsigned short* __restrict__ vfrag,
    unsigned short* __restrict__ pout, float* __restrict__ pl,
    const float* __restrict__ X, const float* __restrict__ gamma,
    float* __restrict__ out)
{
    __shared__ alignas(16) short klds[2][1024];   // 2 x 32-key K frags
    __shared__ alignas(16) short vlds[2][4096];   // 8 V slabs

    const int t = threadIdx.x;
    const int w = t >> 6, lane = t & 63;
    const int h = lane >> 5, q = lane & 31;

    const int nwg = gridDim.x;
    const int cpx = nwg >> 3;
    const int bid = (blockIdx.x & 7) * cpx + (blockIdx.x >> 3);

    const int qtile = bid & 15;
    const int b = (bid >> 4) & 7;
    const int ks = bid >> 7;

    const int qbase = qtile * 256 + w * 64;

    bf16x8 qfA = {}, qfB = {};
    if (h == 0) {
        qfA = *(const bf16x8*)(qw + ((size_t)b * NN + qbase + q) * 8);
        qfB = *(const bf16x8*)(qw + ((size_t)b * NN + qbase + 32 + q) * 8);
    }

    f32x16 accA0 = {}, accA1 = {}, accB0 = {}, accB1 = {};
    float lsumA = 0.f, lsumB = 0.f;

    const int NT = NN / KS / 64;
    const int t0 = ks * NT;

    // Per-wave stage: waves 0-3 sweep V slabs {w, w+4}; waves 0,1 also stage
    // the two 32-key K frags. glds dest = wave-uniform base (+lane*16 by HW).
    auto stage = [&](int buf, int gt) {
        const unsigned short* vsrc = vfrag + ((size_t)(b * 64 + gt)) * 4096;
        short* vdst = &vlds[buf][0];
        glds16(vsrc + (size_t)w * 512 + (size_t)lane * 8,       vdst + (size_t)w * 512);
        glds16(vsrc + (size_t)(w + 4) * 512 + (size_t)lane * 8, vdst + (size_t)(w + 4) * 512);
        if (w < 2) {
            const unsigned short* ksrc = kfrag + ((size_t)b * 128 + (size_t)gt * 2 + w) * 512;
            glds16(ksrc + (size_t)lane * 8, &klds[buf][w * 512]);
        }
    };

    // one 32-key phase
    auto phase = [&](bf16x8 kc, bf16x8 va, bf16x8 vb2, bf16x8 vc, bf16x8 vd) {
        f32x16 sA = __builtin_amdgcn_mfma_f32_32x32x16_bf16(kc, qfA, (f32x16){}, 0, 0, 0);
        f32x16 sB = __builtin_amdgcn_mfma_f32_32x32x16_bf16(kc, qfB, (f32x16){}, 0, 0, 0);
        float pa[16], pb[16];
        #pragma unroll
        for (int r = 0; r < 16; ++r) { pa[r] = fast_exp2(sA[r]); pb[r] = fast_exp2(sB[r]); }
        {
            float a0 = 0.f, a1 = 0.f, b0 = 0.f, b1 = 0.f;
            #pragma unroll
            for (int r = 0; r < 8; ++r) {
                a0 += pa[r]; a1 += pa[8 + r];
                b0 += pb[r]; b1 += pb[8 + r];
            }
            lsumA += a0 + a1;
            lsumB += b0 + b1;
        }
        unsigned ka[8], kb2[8];
        #pragma unroll
        for (int j = 0; j < 8; ++j) {
            ka[j]  = cvt_pk_bf16(pa[2 * j], pa[2 * j + 1]);
            kb2[j] = cvt_pk_bf16(pb[2 * j], pb[2 * j + 1]);
        }
        __builtin_amdgcn_s_setprio(1);
        #pragma unroll
        for (int g2 = 0; g2 < 2; ++g2) {
            const unsigned* pga = &ka[4 * g2];
            auto ra = __builtin_amdgcn_permlane32_swap(pga[2], pga[0], false, false);
            auto rb = __builtin_amdgcn_permlane32_swap(pga[3], pga[1], false, false);
            uint4v bua = { ra[1], rb[1], ra[0], rb[0] };
            bf16x8 pfA = __builtin_bit_cast(bf16x8, bua);
            const unsigned* pgb = &kb2[4 * g2];
            auto rc = __builtin_amdgcn_permlane32_swap(pgb[2], pgb[0], false, false);
            auto rd = __builtin_amdgcn_permlane32_swap(pgb[3], pgb[1], false, false);
            uint4v bub = { rc[1], rd[1], rc[0], rd[0] };
            bf16x8 pfB = __builtin_bit_cast(bf16x8, bub);
            bf16x8 vx = g2 ? vc : va;
            bf16x8 vy = g2 ? vd : vb2;
            accA0 = __builtin_amdgcn_mfma_f32_32x32x16_bf16(vx, pfA, accA0, 0, 0, 0);
            accA1 = __builtin_amdgcn_mfma_f32_32x32x16_bf16(vy, pfA, accA1, 0, 0, 0);
            accB0 = __builtin_amdgcn_mfma_f32_32x32x16_bf16(vx, pfB, accB0, 0, 0, 0);
            accB1 = __builtin_amdgcn_mfma_f32_32x32x16_bf16(vy, pfB, accB1, 0, 0, 0);
        }
        __builtin_amdgcn_s_setprio(0);
    };

    stage(0, t0);

    for (int it = 0; it < NT; ++it) {
        const int cur = it & 1;
        if (it + 1 < NT) {
            stage(cur ^ 1, t0 + it + 1);
            // wait for PREVIOUS stage only (just-issued stage stays in flight)
            if (w < 2) vmwait3(); else vmwait2();
        } else {
            vmwait0();
        }
        __builtin_amdgcn_s_barrier();
        __builtin_amdgcn_sched_barrier(0);

        const short* kl = &klds[cur][0];
        const short* vl = &vlds[cur][0];
        bf16x8 kc0 = *(const bf16x8*)(kl + (size_t)lane * 8);
        bf16x8 kc1 = *(const bf16x8*)(kl + 512 + (size_t)lane * 8);
        bf16x8 v0 = *(const bf16x8*)(vl + (size_t)lane * 8);
        bf16x8 v1 = *(const bf16x8*)(vl + 512 + (size_t)lane * 8);
        bf16x8 v2 = *(const bf16x8*)(vl + 1024 + (size_t)lane * 8);
        bf16x8 v3 = *(const bf16x8*)(vl + 1536 + (size_t)lane * 8);
        bf16x8 v4 = *(const bf16x8*)(vl + 2048 + (size_t)lane * 8);
        bf16x8 v5 = *(const bf16x8*)(vl + 2560 + (size_t)lane * 8);
        bf16x8 v6 = *(const bf16x8*)(vl + 3072 + (size_t)lane * 8);
        bf16x8 v7 = *(const bf16x8*)(vl + 3584 + (size_t)lane * 8);

        phase(kc0, v0, v1, v2, v3);   // keys 0..31 of tile
        phase(kc1, v4, v5, v6, v7);   // keys 32..63

        lgkmwait0();                  // all ds_reads of buf[cur] complete
        __builtin_amdgcn_s_barrier(); // safe to overwrite buf[cur]
    }

    auto rsA = __builtin_amdgcn_permlane32_swap(__builtin_bit_cast(unsigned, lsumA),
                                                __builtin_bit_cast(unsigned, lsumA), false, false);
    float ltotA = __builtin_bit_cast(float, rsA[0]) + __builtin_bit_cast(float, rsA[1]);
    auto rsB = __builtin_amdgcn_permlane32_swap(__builtin_bit_cast(unsigned, lsumB),
                                                __builtin_bit_cast(unsigned, lsumB), false, false);
    float ltotB = __builtin_bit_cast(float, rsB[0]) + __builtin_bit_cast(float, rsB[1]);

    const float gm = FUSE ? gamma[0] : 0.f;

    #pragma unroll
    for (int sub = 0; sub < 2; ++sub) {
        const int n = qbase + sub * 32 + q;
        const float ltot = sub ? ltotB : ltotA;
        const f32x16& a0 = sub ? accB0 : accA0;
        const f32x16& a1 = sub ? accB1 : accA1;
        if (FUSE) {
            const float inv = 1.f / ltot;
            #pragma unroll
            for (int ct = 0; ct < 2; ++ct) {
                const f32x16& a = ct ? a1 : a0;
                #pragma unroll
                for (int r = 0; r < 16; ++r) {
                    int c = ct * 32 + (r & 3) + 8 * (r >> 2) + 4 * h;
                    size_t idx = ((size_t)(b * CC + c)) * NN + n;
                    out[idx] = X[idx] + gm * a[r] * inv;
                }
            }
        } else {
            unsigned short* po = pout + (size_t)ks * BB * CC * NN;
            #pragma unroll
            for (int ct = 0; ct < 2; ++ct) {
                const f32x16& a = ct ? a1 : a0;
                #pragma unroll
                for (int r = 0; r < 16; ++r) {
                    int c = ct * 32 + (r & 3) + 8 * (r >> 2) + 4 * h;
                    po[((size_t)(b * CC + c)) * NN + n] =
                        __builtin_bit_cast(unsigned short, __float2bfloat16(a[r]));
                }
            }
            if (h == 0) pl[((size_t)(ks * BB + b)) * NN + n] = ltot;
        }
    }
}

// ---------------------------------------------------------------------------
// Kernel 3: combine KS key-splits (bf16 partials) + epilogue.
// ---------------------------------------------------------------------------
template<int KS>
__global__ __launch_bounds__(256) void combine_kernel(
    const unsigned short* __restrict__ pout, const float* __restrict__ pl,
    const float* __restrict__ X, const float* __restrict__ gamma,
    float* __restrict__ out)
{
    const int idx = blockIdx.x * 256 + threadIdx.x;
    const int n4 = idx & 1023;
    const int c  = (idx >> 10) & 63;
    const int b  = idx >> 16;
    const int n0 = n4 * 4;
    const float gm = gamma[0];
    const size_t base = ((size_t)(b * CC + c)) * NN + n0;

    float4 s = make_float4(0.f, 0.f, 0.f, 0.f);
    float4 L = make_float4(0.f, 0.f, 0.f, 0.f);
    #pragma unroll
    for (int ks = 0; ks < KS; ++ks) {
        ushort4 sv = *(const ushort4*)(pout + (size_t)ks * BB * CC * NN + base);
        float4 lv = *(const float4*)(pl + ((size_t)(ks * BB + b)) * NN + n0);
        s.x += __bfloat162float(__builtin_bit_cast(__hip_bfloat16, sv.x));
        s.y += __bfloat162float(__builtin_bit_cast(__hip_bfloat16, sv.y));
        s.z += __bfloat162float(__builtin_bit_cast(__hip_bfloat16, sv.z));
        s.w += __bfloat162float(__builtin_bit_cast(__hip_bfloat16, sv.w));
        L.x += lv.x; L.y += lv.y; L.z += lv.z; L.w += lv.w;
    }
    float4 x = *(const float4*)(X + base);
    float4 o;
    o.x = x.x + gm * s.x / L.x;
    o.y = x.y + gm * s.y / L.y;
    o.z = x.z + gm * s.z / L.z;
    o.w = x.w + gm * s.w / L.w;
    *(float4*)(out + base) = o;
}

// ---------------------------------------------------------------------------
extern "C" void kernel_launch(void* const* d_in, const int* in_sizes, int n_in,
                              void* d_out, int out_size, void* d_ws, size_t ws_size,
                              hipStream_t stream) {
    const float* X  = (const float*)d_in[0];
    const float* Wq = (const float*)d_in[1];
    const float* bq = (const float*)d_in[2];
    const float* Wk = (const float*)d_in[3];
    const float* bk = (const float*)d_in[4];
    const float* Wv = (const float*)d_in[5];
    const float* bv = (const float*)d_in[6];
    const float* gm = (const float*)d_in[7];
    float* out = (float*)d_out;

    unsigned short* qw    = (unsigned short*)d_ws;
    unsigned short* kfrag = qw + (size_t)BB * NN * 8;
    unsigned short* vfrag = kfrag + (size_t)BB * 128 * 512;
    unsigned short* pout  = vfrag + (size_t)BB * 64 * 4096;
    float* pl = (float*)(pout + (size_t)8 * BB * CC * NN);

    const size_t qkv_bytes = ((size_t)BB * NN * 8 + (size_t)BB * 128 * 512
                            + (size_t)BB * 64 * 4096) * 2;
    const size_t need8 = qkv_bytes + (size_t)8 * BB * CC * NN * 2 + (size_t)8 * BB * NN * 4;
    const size_t need4 = qkv_bytes + (size_t)4 * BB * CC * NN * 2 + (size_t)4 * BB * NN * 4;

    qkv_kernel<<<dim3(640), dim3(256), 0, stream>>>(X, Wq, bq, Wk, bk, Wv, bv, qw, kfrag, vfrag);

    if (ws_size >= need8) {
        attn_kernel<8, false><<<dim3(1024), dim3(256), 0, stream>>>(
            qw, kfrag, vfrag, pout, pl, X, gm, out);
        combine_kernel<8><<<dim3((BB * CC * NN / 4) / 256), dim3(256), 0, stream>>>(
            pout, pl, X, gm, out);
    } else if (ws_size >= need4) {
        float* pl4 = (float*)(pout + (size_t)4 * BB * CC * NN);
        attn_kernel<4, false><<<dim3(512), dim3(256), 0, stream>>>(
            qw, kfrag, vfrag, pout, pl4, X, gm, out);
        combine_kernel<4><<<dim3((BB * CC * NN / 4) / 256), dim3(256), 0, stream>>>(
            pout, pl4, X, gm, out);
    } else {
        attn_kernel<1, true><<<dim3(128), dim3(256), 0, stream>>>(
            qw, kfrag, vfrag, nullptr, nullptr, X, gm, out);
    }
}

// Round 14
// 53.448 us; speedup vs baseline: 4.2867x; 1.0797x over previous
//
#include <hip/hip_runtime.h>
#include <hip/hip_bf16.h>

#define BB 8
#define CC 64
#define NN 4096
#define LOG2E 1.44269504088896340736f

typedef short bf16x8 __attribute__((ext_vector_type(8)));
typedef float f32x16 __attribute__((ext_vector_type(16)));
typedef unsigned int uint4v __attribute__((ext_vector_type(4)));

__device__ __forceinline__ unsigned cvt_pk_bf16(float lo, float hi) {
    unsigned r;
    asm("v_cvt_pk_bf16_f32 %0, %1, %2" : "=v"(r) : "v"(lo), "v"(hi));
    return r;
}

// Schraudolph fast exp2 (2 full-rate VALU ops, no trans pipe).
__device__ __forceinline__ float fast_exp2(float x) {
    int i = (int)__builtin_fmaf(x, 8388608.f, 1064992087.f);
    return __builtin_bit_cast(float, i);
}

// Workspace fragment layouts (all bf16 shorts):
//  qw   [b][n][8]
//  kfrag[b][tile32][lane64][8]  lane<32: K[key][d], lane>=32: zeros
//  vfrag[b][tile64][slab8][lane64][8]

// ---------------------------------------------------------------------------
// Kernel 1: QKV projection, 5 groups x 128 position-tiles = 640 blocks.
// ---------------------------------------------------------------------------
__global__ __launch_bounds__(256) void qkv_kernel(
    const float* __restrict__ X,
    const float* __restrict__ Wq, const float* __restrict__ bq,
    const float* __restrict__ Wk, const float* __restrict__ bk,
    const float* __restrict__ Wv, const float* __restrict__ bv,
    unsigned short* __restrict__ qw, unsigned short* __restrict__ kfrag,
    unsigned short* __restrict__ vfrag)
{
    __shared__ float wbuf[64 * 16];
    __shared__ float bsh[16];
    __shared__ short vsh[16][264];

    const int t = threadIdx.x;
    const int grp = blockIdx.x % 5;
    const int tile = blockIdx.x / 5;
    const int b = tile >> 4;
    const int nb = (tile & 15) << 8;
    const int n = nb + t;

    if (grp == 0) {
        for (int i = t; i < 512; i += 256) {
            int o = i >> 6, c = i & 63;
            wbuf[c * 16 + o]     = Wq[i];
            wbuf[c * 16 + 8 + o] = Wk[i];
        }
        if (t < 8) { bsh[t] = bq[t]; bsh[8 + t] = bk[t]; }
    } else {
        const int cbase = (grp - 1) * 16;
        for (int i = t; i < 1024; i += 256) {
            int o = i >> 6, c = i & 63;
            wbuf[c * 16 + o] = Wv[(cbase + o) * 64 + c];
        }
        if (t < 16) bsh[t] = bv[cbase + t];
    }
    __syncthreads();

    float a[16];
    #pragma unroll
    for (int j = 0; j < 16; j++) a[j] = bsh[j];

    const float* xp = X + (size_t)b * CC * NN + n;
    for (int c = 0; c < 64; c++) {
        float xc = xp[(size_t)c * NN];
        const float4* w4 = (const float4*)&wbuf[c * 16];
        float4 w0 = w4[0], w1 = w4[1], w2 = w4[2], w3 = w4[3];
        a[0]  += w0.x * xc; a[1]  += w0.y * xc; a[2]  += w0.z * xc; a[3]  += w0.w * xc;
        a[4]  += w1.x * xc; a[5]  += w1.y * xc; a[6]  += w1.z * xc; a[7]  += w1.w * xc;
        a[8]  += w2.x * xc; a[9]  += w2.y * xc; a[10] += w2.z * xc; a[11] += w2.w * xc;
        a[12] += w3.x * xc; a[13] += w3.y * xc; a[14] += w3.z * xc; a[15] += w3.w * xc;
    }

    if (grp == 0) {
        alignas(16) __hip_bfloat16 qb8[8], kb8[8];
        #pragma unroll
        for (int d = 0; d < 8; d++) {
            qb8[d] = __float2bfloat16(a[d] * LOG2E);
            kb8[d] = __float2bfloat16(a[8 + d]);
        }
        const size_t g = (size_t)b * NN + n;
        *(int4*)(qw + g * 8) = *(const int4*)qb8;
        size_t kf = ((size_t)b * 128 + (n >> 5)) * 512;
        *(int4*)(kfrag + kf + (size_t)(n & 31) * 8) = *(const int4*)kb8;
        *(int4*)(kfrag + kf + (size_t)(32 + (n & 31)) * 8) = make_int4(0, 0, 0, 0);
    } else {
        const int cbase = (grp - 1) * 16;
        const int qb0 = cbase & 31, ct = cbase >> 5;
        #pragma unroll
        for (int j = 0; j < 16; j++)
            vsh[j][t] = __builtin_bit_cast(short, __float2bfloat16(a[j]));
        __syncthreads();
        #pragma unroll
        for (int rr = 0; rr < 2; ++rr) {
            int r = 2 * t + rr;
            int qq = r & 15, hh = (r >> 4) & 1, gg = (r >> 5) & 3, tau = r >> 7;
            int n0 = tau * 64 + gg * 16 + hh * 8;
            int4 val = *(const int4*)&vsh[qq][n0];
            int gtile = (nb >> 6) + tau;
            size_t dst = ((size_t)(b * 64 + gtile)) * 4096
                       + (size_t)(gg * 2 + ct) * 512
                       + (size_t)(32 * hh + qb0 + qq) * 8;
            *(int4*)(vfrag + dst) = val;
        }
    }
}

// ---------------------------------------------------------------------------
// Kernel 2: MFMA flash attention — no LDS, no barriers. FIX vs R10: all 10
// next-tile loads (8 V + 2 K) are issued into NAMED registers at the top of
// each iteration, then sched_barrier(0) PINS them there (compiler cannot
// sink/serialize them). Current tile computes from registers loaded a full
// tile (~800 cyc) earlier -> L2 latency fully hidden. VGPR budget ~200 ->
// 2 waves/SIMD, enough once latency is covered by ILP.
// ---------------------------------------------------------------------------
template<int KS, bool FUSE>
__global__ __launch_bounds__(256, 2) void attn_kernel(
    const unsigned short* __restrict__ qw,
    const unsigned short* __restrict__ kfrag,
    const unsigned short* __restrict__ vfrag,
    unsigned short* __restrict__ pout, float* __restrict__ pl,
    const float* __restrict__ X, const float* __restrict__ gamma,
    float* __restrict__ out)
{
    const int t = threadIdx.x;
    const int w = t >> 6, lane = t & 63;
    const int h = lane >> 5, q = lane & 31;

    const int nwg = gridDim.x;
    const int cpx = nwg >> 3;
    const int bid = (blockIdx.x & 7) * cpx + (blockIdx.x >> 3);

    const int qtile = bid & 15;
    const int b = (bid >> 4) & 7;
    const int ks = bid >> 7;

    const int qbase = qtile * 256 + w * 64;

    bf16x8 qfA = {}, qfB = {};
    if (h == 0) {
        qfA = *(const bf16x8*)(qw + ((size_t)b * NN + qbase + q) * 8);
        qfB = *(const bf16x8*)(qw + ((size_t)b * NN + qbase + 32 + q) * 8);
    }

    f32x16 accA0 = {}, accA1 = {}, accB0 = {}, accB1 = {};
    float lsumA = 0.f, lsumB = 0.f;

    const int NT = NN / KS / 64;
    const unsigned short* kb = kfrag + (size_t)b * 65536
                             + (size_t)ks * NT * 1024 + (size_t)lane * 8;
    const unsigned short* vbp = vfrag + (size_t)b * 262144
                              + (size_t)ks * NT * 4096 + (size_t)lane * 8;

    auto phase = [&](bf16x8 kc, bf16x8 va, bf16x8 vb2, bf16x8 vc, bf16x8 vd) {
        f32x16 sA = __builtin_amdgcn_mfma_f32_32x32x16_bf16(kc, qfA, (f32x16){}, 0, 0, 0);
        f32x16 sB = __builtin_amdgcn_mfma_f32_32x32x16_bf16(kc, qfB, (f32x16){}, 0, 0, 0);
        float pa[16], pb[16];
        #pragma unroll
        for (int r = 0; r < 16; ++r) { pa[r] = fast_exp2(sA[r]); pb[r] = fast_exp2(sB[r]); }
        {
            float a0 = 0.f, a1 = 0.f, b0 = 0.f, b1 = 0.f;
            #pragma unroll
            for (int r = 0; r < 8; ++r) {
                a0 += pa[r]; a1 += pa[8 + r];
                b0 += pb[r]; b1 += pb[8 + r];
            }
            lsumA += a0 + a1;
            lsumB += b0 + b1;
        }
        unsigned ka[8], kb2[8];
        #pragma unroll
        for (int j = 0; j < 8; ++j) {
            ka[j]  = cvt_pk_bf16(pa[2 * j], pa[2 * j + 1]);
            kb2[j] = cvt_pk_bf16(pb[2 * j], pb[2 * j + 1]);
        }
        __builtin_amdgcn_s_setprio(1);
        #pragma unroll
        for (int g2 = 0; g2 < 2; ++g2) {
            const unsigned* pga = &ka[4 * g2];
            auto ra = __builtin_amdgcn_permlane32_swap(pga[2], pga[0], false, false);
            auto rb = __builtin_amdgcn_permlane32_swap(pga[3], pga[1], false, false);
            uint4v bua = { ra[1], rb[1], ra[0], rb[0] };
            bf16x8 pfA = __builtin_bit_cast(bf16x8, bua);
            const unsigned* pgb = &kb2[4 * g2];
            auto rc = __builtin_amdgcn_permlane32_swap(pgb[2], pgb[0], false, false);
            auto rd = __builtin_amdgcn_permlane32_swap(pgb[3], pgb[1], false, false);
            uint4v bub = { rc[1], rd[1], rc[0], rd[0] };
            bf16x8 pfB = __builtin_bit_cast(bf16x8, bub);
            bf16x8 vx = g2 ? vc : va;
            bf16x8 vy = g2 ? vd : vb2;
            accA0 = __builtin_amdgcn_mfma_f32_32x32x16_bf16(vx, pfA, accA0, 0, 0, 0);
            accA1 = __builtin_amdgcn_mfma_f32_32x32x16_bf16(vy, pfA, accA1, 0, 0, 0);
            accB0 = __builtin_amdgcn_mfma_f32_32x32x16_bf16(vx, pfB, accB0, 0, 0, 0);
            accB1 = __builtin_amdgcn_mfma_f32_32x32x16_bf16(vy, pfB, accB1, 0, 0, 0);
        }
        __builtin_amdgcn_s_setprio(0);
    };

    // prologue: load tile 0 into current regs
    bf16x8 kc0 = *(const bf16x8*)kb;
    bf16x8 kc1 = *(const bf16x8*)(kb + 512);
    bf16x8 vc0 = *(const bf16x8*)(vbp);
    bf16x8 vc1 = *(const bf16x8*)(vbp + 512);
    bf16x8 vc2 = *(const bf16x8*)(vbp + 1024);
    bf16x8 vc3 = *(const bf16x8*)(vbp + 1536);
    bf16x8 vc4 = *(const bf16x8*)(vbp + 2048);
    bf16x8 vc5 = *(const bf16x8*)(vbp + 2560);
    bf16x8 vc6 = *(const bf16x8*)(vbp + 3072);
    bf16x8 vc7 = *(const bf16x8*)(vbp + 3584);

    for (int it = 0; it < NT; ++it) {
        // ---- issue ALL next-tile loads, then PIN them with sched_barrier ----
        const int nit = (it + 1 < NT) ? it + 1 : it;
        const unsigned short* knp = kb + (size_t)nit * 1024;
        const unsigned short* vnp = vbp + (size_t)nit * 4096;
        bf16x8 kn0 = *(const bf16x8*)knp;
        bf16x8 kn1 = *(const bf16x8*)(knp + 512);
        bf16x8 vn0 = *(const bf16x8*)(vnp);
        bf16x8 vn1 = *(const bf16x8*)(vnp + 512);
        bf16x8 vn2 = *(const bf16x8*)(vnp + 1024);
        bf16x8 vn3 = *(const bf16x8*)(vnp + 1536);
        bf16x8 vn4 = *(const bf16x8*)(vnp + 2048);
        bf16x8 vn5 = *(const bf16x8*)(vnp + 2560);
        bf16x8 vn6 = *(const bf16x8*)(vnp + 3072);
        bf16x8 vn7 = *(const bf16x8*)(vnp + 3584);
        __builtin_amdgcn_sched_barrier(0);   // loads may NOT sink below this

        // ---- compute current tile (regs loaded a full tile ago) ----
        phase(kc0, vc0, vc1, vc2, vc3);   // keys 0..31
        phase(kc1, vc4, vc5, vc6, vc7);   // keys 32..63

        // rotate
        kc0 = kn0; kc1 = kn1;
        vc0 = vn0; vc1 = vn1; vc2 = vn2; vc3 = vn3;
        vc4 = vn4; vc5 = vn5; vc6 = vn6; vc7 = vn7;
    }

    auto rsA = __builtin_amdgcn_permlane32_swap(__builtin_bit_cast(unsigned, lsumA),
                                                __builtin_bit_cast(unsigned, lsumA), false, false);
    float ltotA = __builtin_bit_cast(float, rsA[0]) + __builtin_bit_cast(float, rsA[1]);
    auto rsB = __builtin_amdgcn_permlane32_swap(__builtin_bit_cast(unsigned, lsumB),
                                                __builtin_bit_cast(unsigned, lsumB), false, false);
    float ltotB = __builtin_bit_cast(float, rsB[0]) + __builtin_bit_cast(float, rsB[1]);

    const float gm = FUSE ? gamma[0] : 0.f;

    #pragma unroll
    for (int sub = 0; sub < 2; ++sub) {
        const int n = qbase + sub * 32 + q;
        const float ltot = sub ? ltotB : ltotA;
        const f32x16& a0 = sub ? accB0 : accA0;
        const f32x16& a1 = sub ? accB1 : accA1;
        if (FUSE) {
            const float inv = 1.f / ltot;
            #pragma unroll
            for (int ct = 0; ct < 2; ++ct) {
                const f32x16& a = ct ? a1 : a0;
                #pragma unroll
                for (int r = 0; r < 16; ++r) {
                    int c = ct * 32 + (r & 3) + 8 * (r >> 2) + 4 * h;
                    size_t idx = ((size_t)(b * CC + c)) * NN + n;
                    out[idx] = X[idx] + gm * a[r] * inv;
                }
            }
        } else {
            unsigned short* po = pout + (size_t)ks * BB * CC * NN;
            #pragma unroll
            for (int ct = 0; ct < 2; ++ct) {
                const f32x16& a = ct ? a1 : a0;
                #pragma unroll
                for (int r = 0; r < 16; ++r) {
                    int c = ct * 32 + (r & 3) + 8 * (r >> 2) + 4 * h;
                    po[((size_t)(b * CC + c)) * NN + n] =
                        __builtin_bit_cast(unsigned short, __float2bfloat16(a[r]));
                }
            }
            if (h == 0) pl[((size_t)(ks * BB + b)) * NN + n] = ltot;
        }
    }
}

// ---------------------------------------------------------------------------
// Kernel 3: combine KS key-splits (bf16 partials) + epilogue.
// ---------------------------------------------------------------------------
template<int KS>
__global__ __launch_bounds__(256) void combine_kernel(
    const unsigned short* __restrict__ pout, const float* __restrict__ pl,
    const float* __restrict__ X, const float* __restrict__ gamma,
    float* __restrict__ out)
{
    const int idx = blockIdx.x * 256 + threadIdx.x;
    const int n4 = idx & 1023;
    const int c  = (idx >> 10) & 63;
    const int b  = idx >> 16;
    const int n0 = n4 * 4;
    const float gm = gamma[0];
    const size_t base = ((size_t)(b * CC + c)) * NN + n0;

    float4 s = make_float4(0.f, 0.f, 0.f, 0.f);
    float4 L = make_float4(0.f, 0.f, 0.f, 0.f);
    #pragma unroll
    for (int ks = 0; ks < KS; ++ks) {
        ushort4 sv = *(const ushort4*)(pout + (size_t)ks * BB * CC * NN + base);
        float4 lv = *(const float4*)(pl + ((size_t)(ks * BB + b)) * NN + n0);
        s.x += __bfloat162float(__builtin_bit_cast(__hip_bfloat16, sv.x));
        s.y += __bfloat162float(__builtin_bit_cast(__hip_bfloat16, sv.y));
        s.z += __bfloat162float(__builtin_bit_cast(__hip_bfloat16, sv.z));
        s.w += __bfloat162float(__builtin_bit_cast(__hip_bfloat16, sv.w));
        L.x += lv.x; L.y += lv.y; L.z += lv.z; L.w += lv.w;
    }
    float4 x = *(const float4*)(X + base);
    float4 o;
    o.x = x.x + gm * s.x / L.x;
    o.y = x.y + gm * s.y / L.y;
    o.z = x.z + gm * s.z / L.z;
    o.w = x.w + gm * s.w / L.w;
    *(float4*)(out + base) = o;
}

// ---------------------------------------------------------------------------
extern "C" void kernel_launch(void* const* d_in, const int* in_sizes, int n_in,
                              void* d_out, int out_size, void* d_ws, size_t ws_size,
                              hipStream_t stream) {
    const float* X  = (const float*)d_in[0];
    const float* Wq = (const float*)d_in[1];
    const float* bq = (const float*)d_in[2];
    const float* Wk = (const float*)d_in[3];
    const float* bk = (const float*)d_in[4];
    const float* Wv = (const float*)d_in[5];
    const float* bv = (const float*)d_in[6];
    const float* gm = (const float*)d_in[7];
    float* out = (float*)d_out;

    unsigned short* qw    = (unsigned short*)d_ws;
    unsigned short* kfrag = qw + (size_t)BB * NN * 8;
    unsigned short* vfrag = kfrag + (size_t)BB * 128 * 512;
    unsigned short* pout  = vfrag + (size_t)BB * 64 * 4096;
    float* pl = (float*)(pout + (size_t)4 * BB * CC * NN);

    const size_t qkv_bytes = ((size_t)BB * NN * 8 + (size_t)BB * 128 * 512
                            + (size_t)BB * 64 * 4096) * 2;
    const size_t need4 = qkv_bytes + (size_t)4 * BB * CC * NN * 2 + (size_t)4 * BB * NN * 4;

    qkv_kernel<<<dim3(640), dim3(256), 0, stream>>>(X, Wq, bq, Wk, bk, Wv, bv, qw, kfrag, vfrag);

    if (ws_size >= need4) {
        attn_kernel<4, false><<<dim3(512), dim3(256), 0, stream>>>(
            qw, kfrag, vfrag, pout, pl, X, gm, out);
        combine_kernel<4><<<dim3((BB * CC * NN / 4) / 256), dim3(256), 0, stream>>>(
            pout, pl, X, gm, out);
    } else {
        attn_kernel<1, true><<<dim3(128), dim3(256), 0, stream>>>(
            qw, kfrag, vfrag, nullptr, nullptr, X, gm, out);
    }
}

// Round 15
// 52.781 us; speedup vs baseline: 4.3408x; 1.0126x over previous
//
#include <hip/hip_runtime.h>
#include <hip/hip_bf16.h>

#define BB 8
#define CC 64
#define NN 4096
#define LOG2E 1.44269504088896340736f

typedef short bf16x8 __attribute__((ext_vector_type(8)));
typedef float f32x16 __attribute__((ext_vector_type(16)));
typedef float f32x2 __attribute__((ext_vector_type(2)));
typedef unsigned int uint4v __attribute__((ext_vector_type(4)));

__device__ __forceinline__ unsigned cvt_pk_bf16(float lo, float hi) {
    unsigned r;
    asm("v_cvt_pk_bf16_f32 %0, %1, %2" : "=v"(r) : "v"(lo), "v"(hi));
    return r;
}

// Packed (2-wide) full-rate f32 ops, VOP3P (gfx90a+/CDNA).
__device__ __forceinline__ f32x2 pk_fma(f32x2 a, f32x2 b, f32x2 c) {
    f32x2 d;
    asm("v_pk_fma_f32 %0, %1, %2, %3" : "=v"(d) : "v"(a), "v"(b), "v"(c));
    return d;
}
__device__ __forceinline__ f32x2 pk_add(f32x2 a, f32x2 b) {
    f32x2 d;
    asm("v_pk_add_f32 %0, %1, %2" : "=v"(d) : "v"(a), "v"(b));
    return d;
}

// Workspace fragment layouts (all bf16 shorts):
//  qw   [b][n][8]
//  kfrag[b][tile32][lane64][8]  lane<32: K[key][d], lane>=32: zeros
//  vfrag[b][tile64][slab8][lane64][8]

// ---------------------------------------------------------------------------
// Kernel 1: QKV projection, 5 groups x 128 position-tiles = 640 blocks.
// X loads batched 8-wide + ping-pong prefetch (breaks the 64-deep serial
// load->fma chain that made this kernel latency-bound).
// ---------------------------------------------------------------------------
__global__ __launch_bounds__(256) void qkv_kernel(
    const float* __restrict__ X,
    const float* __restrict__ Wq, const float* __restrict__ bq,
    const float* __restrict__ Wk, const float* __restrict__ bk,
    const float* __restrict__ Wv, const float* __restrict__ bv,
    unsigned short* __restrict__ qw, unsigned short* __restrict__ kfrag,
    unsigned short* __restrict__ vfrag)
{
    __shared__ float wbuf[64 * 16];
    __shared__ float bsh[16];
    __shared__ short vsh[16][264];

    const int t = threadIdx.x;
    const int grp = blockIdx.x % 5;
    const int tile = blockIdx.x / 5;
    const int b = tile >> 4;
    const int nb = (tile & 15) << 8;
    const int n = nb + t;

    if (grp == 0) {
        for (int i = t; i < 512; i += 256) {
            int o = i >> 6, c = i & 63;
            wbuf[c * 16 + o]     = Wq[i];
            wbuf[c * 16 + 8 + o] = Wk[i];
        }
        if (t < 8) { bsh[t] = bq[t]; bsh[8 + t] = bk[t]; }
    } else {
        const int cbase = (grp - 1) * 16;
        for (int i = t; i < 1024; i += 256) {
            int o = i >> 6, c = i & 63;
            wbuf[c * 16 + o] = Wv[(cbase + o) * 64 + c];
        }
        if (t < 16) bsh[t] = bv[cbase + t];
    }
    __syncthreads();

    float a[16];
    #pragma unroll
    for (int j = 0; j < 16; j++) a[j] = bsh[j];

    const float* xp = X + (size_t)b * CC * NN + n;

    float xa[8], xb2[8];
    auto loadx = [&](float (&xs)[8], int cb) {
        #pragma unroll
        for (int j = 0; j < 8; j++) xs[j] = xp[(size_t)(cb + j) * NN];
    };
    auto fmab = [&](const float (&xs)[8], int cb) {
        #pragma unroll
        for (int j = 0; j < 8; j++) {
            float xc = xs[j];
            const float4* w4 = (const float4*)&wbuf[(cb + j) * 16];
            float4 w0 = w4[0], w1 = w4[1], w2 = w4[2], w3 = w4[3];
            a[0]  += w0.x * xc; a[1]  += w0.y * xc; a[2]  += w0.z * xc; a[3]  += w0.w * xc;
            a[4]  += w1.x * xc; a[5]  += w1.y * xc; a[6]  += w1.z * xc; a[7]  += w1.w * xc;
            a[8]  += w2.x * xc; a[9]  += w2.y * xc; a[10] += w2.z * xc; a[11] += w2.w * xc;
            a[12] += w3.x * xc; a[13] += w3.y * xc; a[14] += w3.z * xc; a[15] += w3.w * xc;
        }
    };

    loadx(xa, 0);
    #pragma unroll
    for (int cb = 0; cb < 64; cb += 16) {
        loadx(xb2, cb + 8);
        __builtin_amdgcn_sched_barrier(0);
        fmab(xa, cb);
        if (cb + 16 < 64) loadx(xa, cb + 16);
        __builtin_amdgcn_sched_barrier(0);
        fmab(xb2, cb + 8);
    }

    if (grp == 0) {
        alignas(16) __hip_bfloat16 qb8[8], kb8[8];
        #pragma unroll
        for (int d = 0; d < 8; d++) {
            qb8[d] = __float2bfloat16(a[d] * LOG2E);
            kb8[d] = __float2bfloat16(a[8 + d]);
        }
        const size_t g = (size_t)b * NN + n;
        *(int4*)(qw + g * 8) = *(const int4*)qb8;
        size_t kf = ((size_t)b * 128 + (n >> 5)) * 512;
        *(int4*)(kfrag + kf + (size_t)(n & 31) * 8) = *(const int4*)kb8;
        *(int4*)(kfrag + kf + (size_t)(32 + (n & 31)) * 8) = make_int4(0, 0, 0, 0);
    } else {
        const int cbase = (grp - 1) * 16;
        const int qb0 = cbase & 31, ct = cbase >> 5;
        #pragma unroll
        for (int j = 0; j < 16; j++)
            vsh[j][t] = __builtin_bit_cast(short, __float2bfloat16(a[j]));
        __syncthreads();
        #pragma unroll
        for (int rr = 0; rr < 2; ++rr) {
            int r = 2 * t + rr;
            int qq = r & 15, hh = (r >> 4) & 1, gg = (r >> 5) & 3, tau = r >> 7;
            int n0 = tau * 64 + gg * 16 + hh * 8;
            int4 val = *(const int4*)&vsh[qq][n0];
            int gtile = (nb >> 6) + tau;
            size_t dst = ((size_t)(b * 64 + gtile)) * 4096
                       + (size_t)(gg * 2 + ct) * 512
                       + (size_t)(32 * hh + qb0 + qq) * 8;
            *(int4*)(vfrag + dst) = val;
        }
    }
}

// ---------------------------------------------------------------------------
// Kernel 2: MFMA flash attention — no LDS, no barriers, pinned next-tile
// register prefetch (R14). NEW: softmax core in packed 2-wide VALU ops
// (v_pk_fma_f32 Schraudolph + v_pk_add_f32 running sums) -> ~27% fewer
// core VALU instructions per softmax element.
// ---------------------------------------------------------------------------
template<int KS, bool FUSE>
__global__ __launch_bounds__(256, 2) void attn_kernel(
    const unsigned short* __restrict__ qw,
    const unsigned short* __restrict__ kfrag,
    const unsigned short* __restrict__ vfrag,
    unsigned short* __restrict__ pout, float* __restrict__ pl,
    const float* __restrict__ X, const float* __restrict__ gamma,
    float* __restrict__ out)
{
    const int t = threadIdx.x;
    const int w = t >> 6, lane = t & 63;
    const int h = lane >> 5, q = lane & 31;

    const int nwg = gridDim.x;
    const int cpx = nwg >> 3;
    const int bid = (blockIdx.x & 7) * cpx + (blockIdx.x >> 3);

    const int qtile = bid & 15;
    const int b = (bid >> 4) & 7;
    const int ks = bid >> 7;

    const int qbase = qtile * 256 + w * 64;

    bf16x8 qfA = {}, qfB = {};
    if (h == 0) {
        qfA = *(const bf16x8*)(qw + ((size_t)b * NN + qbase + q) * 8);
        qfB = *(const bf16x8*)(qw + ((size_t)b * NN + qbase + 32 + q) * 8);
    }

    f32x16 accA0 = {}, accA1 = {}, accB0 = {}, accB1 = {};
    f32x2 lsA2 = {0.f, 0.f}, lsB2 = {0.f, 0.f};

    const f32x2 kSc = {8388608.f, 8388608.f};
    const f32x2 kBi = {1064992087.f, 1064992087.f};

    const int NT = NN / KS / 64;
    const unsigned short* kb = kfrag + (size_t)b * 65536
                             + (size_t)ks * NT * 1024 + (size_t)lane * 8;
    const unsigned short* vbp = vfrag + (size_t)b * 262144
                              + (size_t)ks * NT * 4096 + (size_t)lane * 8;

    auto phase = [&](bf16x8 kc, bf16x8 va, bf16x8 vb2, bf16x8 vc, bf16x8 vd) {
        f32x16 sA = __builtin_amdgcn_mfma_f32_32x32x16_bf16(kc, qfA, (f32x16){}, 0, 0, 0);
        f32x16 sB = __builtin_amdgcn_mfma_f32_32x32x16_bf16(kc, qfB, (f32x16){}, 0, 0, 0);

        // packed Schraudolph exp2 + packed running sums
        float pa[16], pb[16];
        #pragma unroll
        for (int r = 0; r < 8; ++r) {
            f32x2 sa2 = { sA[2 * r], sA[2 * r + 1] };
            f32x2 ya = pk_fma(sa2, kSc, kBi);
            pa[2 * r]     = __builtin_bit_cast(float, (int)ya[0]);
            pa[2 * r + 1] = __builtin_bit_cast(float, (int)ya[1]);
            lsA2 = pk_add(lsA2, (f32x2){ pa[2 * r], pa[2 * r + 1] });
            f32x2 sb2 = { sB[2 * r], sB[2 * r + 1] };
            f32x2 yb = pk_fma(sb2, kSc, kBi);
            pb[2 * r]     = __builtin_bit_cast(float, (int)yb[0]);
            pb[2 * r + 1] = __builtin_bit_cast(float, (int)yb[1]);
            lsB2 = pk_add(lsB2, (f32x2){ pb[2 * r], pb[2 * r + 1] });
        }

        unsigned ka[8], kb2[8];
        #pragma unroll
        for (int j = 0; j < 8; ++j) {
            ka[j]  = cvt_pk_bf16(pa[2 * j], pa[2 * j + 1]);
            kb2[j] = cvt_pk_bf16(pb[2 * j], pb[2 * j + 1]);
        }
        __builtin_amdgcn_s_setprio(1);
        #pragma unroll
        for (int g2 = 0; g2 < 2; ++g2) {
            const unsigned* pga = &ka[4 * g2];
            auto ra = __builtin_amdgcn_permlane32_swap(pga[2], pga[0], false, false);
            auto rb = __builtin_amdgcn_permlane32_swap(pga[3], pga[1], false, false);
            uint4v bua = { ra[1], rb[1], ra[0], rb[0] };
            bf16x8 pfA = __builtin_bit_cast(bf16x8, bua);
            const unsigned* pgb = &kb2[4 * g2];
            auto rc = __builtin_amdgcn_permlane32_swap(pgb[2], pgb[0], false, false);
            auto rd = __builtin_amdgcn_permlane32_swap(pgb[3], pgb[1], false, false);
            uint4v bub = { rc[1], rd[1], rc[0], rd[0] };
            bf16x8 pfB = __builtin_bit_cast(bf16x8, bub);
            bf16x8 vx = g2 ? vc : va;
            bf16x8 vy = g2 ? vd : vb2;
            accA0 = __builtin_amdgcn_mfma_f32_32x32x16_bf16(vx, pfA, accA0, 0, 0, 0);
            accA1 = __builtin_amdgcn_mfma_f32_32x32x16_bf16(vy, pfA, accA1, 0, 0, 0);
            accB0 = __builtin_amdgcn_mfma_f32_32x32x16_bf16(vx, pfB, accB0, 0, 0, 0);
            accB1 = __builtin_amdgcn_mfma_f32_32x32x16_bf16(vy, pfB, accB1, 0, 0, 0);
        }
        __builtin_amdgcn_s_setprio(0);
    };

    // prologue: load tile 0 into current regs
    bf16x8 kc0 = *(const bf16x8*)kb;
    bf16x8 kc1 = *(const bf16x8*)(kb + 512);
    bf16x8 vc0 = *(const bf16x8*)(vbp);
    bf16x8 vc1 = *(const bf16x8*)(vbp + 512);
    bf16x8 vc2 = *(const bf16x8*)(vbp + 1024);
    bf16x8 vc3 = *(const bf16x8*)(vbp + 1536);
    bf16x8 vc4 = *(const bf16x8*)(vbp + 2048);
    bf16x8 vc5 = *(const bf16x8*)(vbp + 2560);
    bf16x8 vc6 = *(const bf16x8*)(vbp + 3072);
    bf16x8 vc7 = *(const bf16x8*)(vbp + 3584);

    for (int it = 0; it < NT; ++it) {
        const int nit = (it + 1 < NT) ? it + 1 : it;
        const unsigned short* knp = kb + (size_t)nit * 1024;
        const unsigned short* vnp = vbp + (size_t)nit * 4096;
        bf16x8 kn0 = *(const bf16x8*)knp;
        bf16x8 kn1 = *(const bf16x8*)(knp + 512);
        bf16x8 vn0 = *(const bf16x8*)(vnp);
        bf16x8 vn1 = *(const bf16x8*)(vnp + 512);
        bf16x8 vn2 = *(const bf16x8*)(vnp + 1024);
        bf16x8 vn3 = *(const bf16x8*)(vnp + 1536);
        bf16x8 vn4 = *(const bf16x8*)(vnp + 2048);
        bf16x8 vn5 = *(const bf16x8*)(vnp + 2560);
        bf16x8 vn6 = *(const bf16x8*)(vnp + 3072);
        bf16x8 vn7 = *(const bf16x8*)(vnp + 3584);
        __builtin_amdgcn_sched_barrier(0);   // loads may NOT sink below this

        phase(kc0, vc0, vc1, vc2, vc3);   // keys 0..31
        phase(kc1, vc4, vc5, vc6, vc7);   // keys 32..63

        kc0 = kn0; kc1 = kn1;
        vc0 = vn0; vc1 = vn1; vc2 = vn2; vc3 = vn3;
        vc4 = vn4; vc5 = vn5; vc6 = vn6; vc7 = vn7;
    }

    float lsumA = lsA2[0] + lsA2[1];
    float lsumB = lsB2[0] + lsB2[1];

    auto rsA = __builtin_amdgcn_permlane32_swap(__builtin_bit_cast(unsigned, lsumA),
                                                __builtin_bit_cast(unsigned, lsumA), false, false);
    float ltotA = __builtin_bit_cast(float, rsA[0]) + __builtin_bit_cast(float, rsA[1]);
    auto rsB = __builtin_amdgcn_permlane32_swap(__builtin_bit_cast(unsigned, lsumB),
                                                __builtin_bit_cast(unsigned, lsumB), false, false);
    float ltotB = __builtin_bit_cast(float, rsB[0]) + __builtin_bit_cast(float, rsB[1]);

    const float gm = FUSE ? gamma[0] : 0.f;

    #pragma unroll
    for (int sub = 0; sub < 2; ++sub) {
        const int n = qbase + sub * 32 + q;
        const float ltot = sub ? ltotB : ltotA;
        const f32x16& a0 = sub ? accB0 : accA0;
        const f32x16& a1 = sub ? accB1 : accA1;
        if (FUSE) {
            const float inv = 1.f / ltot;
            #pragma unroll
            for (int ct = 0; ct < 2; ++ct) {
                const f32x16& a = ct ? a1 : a0;
                #pragma unroll
                for (int r = 0; r < 16; ++r) {
                    int c = ct * 32 + (r & 3) + 8 * (r >> 2) + 4 * h;
                    size_t idx = ((size_t)(b * CC + c)) * NN + n;
                    out[idx] = X[idx] + gm * a[r] * inv;
                }
            }
        } else {
            unsigned short* po = pout + (size_t)ks * BB * CC * NN;
            #pragma unroll
            for (int ct = 0; ct < 2; ++ct) {
                const f32x16& a = ct ? a1 : a0;
                #pragma unroll
                for (int r = 0; r < 16; ++r) {
                    int c = ct * 32 + (r & 3) + 8 * (r >> 2) + 4 * h;
                    po[((size_t)(b * CC + c)) * NN + n] =
                        __builtin_bit_cast(unsigned short, __float2bfloat16(a[r]));
                }
            }
            if (h == 0) pl[((size_t)(ks * BB + b)) * NN + n] = ltot;
        }
    }
}

// ---------------------------------------------------------------------------
// Kernel 3: combine KS key-splits (bf16 partials) + epilogue.
// ---------------------------------------------------------------------------
template<int KS>
__global__ __launch_bounds__(256) void combine_kernel(
    const unsigned short* __restrict__ pout, const float* __restrict__ pl,
    const float* __restrict__ X, const float* __restrict__ gamma,
    float* __restrict__ out)
{
    const int idx = blockIdx.x * 256 + threadIdx.x;
    const int n4 = idx & 1023;
    const int c  = (idx >> 10) & 63;
    const int b  = idx >> 16;
    const int n0 = n4 * 4;
    const float gm = gamma[0];
    const size_t base = ((size_t)(b * CC + c)) * NN + n0;

    float4 s = make_float4(0.f, 0.f, 0.f, 0.f);
    float4 L = make_float4(0.f, 0.f, 0.f, 0.f);
    #pragma unroll
    for (int ks = 0; ks < KS; ++ks) {
        ushort4 sv = *(const ushort4*)(pout + (size_t)ks * BB * CC * NN + base);
        float4 lv = *(const float4*)(pl + ((size_t)(ks * BB + b)) * NN + n0);
        s.x += __bfloat162float(__builtin_bit_cast(__hip_bfloat16, sv.x));
        s.y += __bfloat162float(__builtin_bit_cast(__hip_bfloat16, sv.y));
        s.z += __bfloat162float(__builtin_bit_cast(__hip_bfloat16, sv.z));
        s.w += __bfloat162float(__builtin_bit_cast(__hip_bfloat16, sv.w));
        L.x += lv.x; L.y += lv.y; L.z += lv.z; L.w += lv.w;
    }
    float4 x = *(const float4*)(X + base);
    float4 o;
    o.x = x.x + gm * s.x / L.x;
    o.y = x.y + gm * s.y / L.y;
    o.z = x.z + gm * s.z / L.z;
    o.w = x.w + gm * s.w / L.w;
    *(float4*)(out + base) = o;
}

// ---------------------------------------------------------------------------
extern "C" void kernel_launch(void* const* d_in, const int* in_sizes, int n_in,
                              void* d_out, int out_size, void* d_ws, size_t ws_size,
                              hipStream_t stream) {
    const float* X  = (const float*)d_in[0];
    const float* Wq = (const float*)d_in[1];
    const float* bq = (const float*)d_in[2];
    const float* Wk = (const float*)d_in[3];
    const float* bk = (const float*)d_in[4];
    const float* Wv = (const float*)d_in[5];
    const float* bv = (const float*)d_in[6];
    const float* gm = (const float*)d_in[7];
    float* out = (float*)d_out;

    unsigned short* qw    = (unsigned short*)d_ws;
    unsigned short* kfrag = qw + (size_t)BB * NN * 8;
    unsigned short* vfrag = kfrag + (size_t)BB * 128 * 512;
    unsigned short* pout  = vfrag + (size_t)BB * 64 * 4096;
    float* pl = (float*)(pout + (size_t)4 * BB * CC * NN);

    const size_t qkv_bytes = ((size_t)BB * NN * 8 + (size_t)BB * 128 * 512
                            + (size_t)BB * 64 * 4096) * 2;
    const size_t need4 = qkv_bytes + (size_t)4 * BB * CC * NN * 2 + (size_t)4 * BB * NN * 4;

    qkv_kernel<<<dim3(640), dim3(256), 0, stream>>>(X, Wq, bq, Wk, bk, Wv, bv, qw, kfrag, vfrag);

    if (ws_size >= need4) {
        attn_kernel<4, false><<<dim3(512), dim3(256), 0, stream>>>(
            qw, kfrag, vfrag, pout, pl, X, gm, out);
        combine_kernel<4><<<dim3((BB * CC * NN / 4) / 256), dim3(256), 0, stream>>>(
            pout, pl, X, gm, out);
    } else {
        attn_kernel<1, true><<<dim3(128), dim3(256), 0, stream>>>(
            qw, kfrag, vfrag, nullptr, nullptr, X, gm, out);
    }
}